// Round 16
// baseline (133.625 us; speedup 1.0000x reference)
//
#include <hip/hip_runtime.h>
#include <math.h>

// Problem: B=8, C=256, N=H*W=1024, nh=8, dk=dv=32. fp32 in/out, bf16 ws.
// Round 33: flash-decoding split-K for K2. Evidence: K2 invariant ~31us
// across r22/r30/r32 structures; per-chunk wall ~9k cy vs ~1.6k work ->
// serial 8-chunk chain dominates. Split: 2048 blocks, each (qtile,bh,half)
// does 512 keys = 4 chunks (single-buffered LDS 18.9KB, 2 barriers/chunk,
// prefetch-after-barrier), writes UNNORMALIZED fp32 partials (O, m, l).
// r33_merge combines halves (flash combine) -> bf16 ows. Extra dispatch is
// free (r24: gap ~ 0). K1 = r22 verbatim, K3 = r29 verbatim.
typedef unsigned short u16;
typedef __attribute__((ext_vector_type(8))) unsigned short u16x8;
typedef __attribute__((ext_vector_type(8))) short s16x8;   // MFMA A/B frag
typedef __attribute__((ext_vector_type(4))) float f32x4;   // MFMA C/D

// logits scale 1/sqrt(32) folded with log2(e) so softmax uses exp2 directly
#define QK_SCALE (0.17677669529663687f * 1.4426950408889634f)

__device__ __forceinline__ unsigned cvt2(float lo, float hi) {
  unsigned r;  // D[15:0]=bf16_rne(lo), D[31:16]=bf16_rne(hi)
  asm("v_cvt_pk_bf16_f32 %0, %1, %2" : "=v"(r) : "v"(lo), "v"(hi));
  return r;
}
__device__ __forceinline__ u16 f2bf(float f) { return (u16)cvt2(f, f); }
__device__ __forceinline__ u16x8 ld16(const void* p) { u16x8 v; __builtin_memcpy(&v, p, 16); return v; }
__device__ __forceinline__ void st16(void* p, u16x8 v) { __builtin_memcpy(p, &v, 16); }
__device__ __forceinline__ void st4(void* p, unsigned v) { __builtin_memcpy(p, &v, 4); }
__device__ __forceinline__ void st8(void* p, unsigned lo, unsigned hi) {
  unsigned long long v = ((unsigned long long)hi << 32) | (unsigned long long)lo;
  __builtin_memcpy(p, &v, 8);
}
__device__ __forceinline__ f32x4 ldf4(const void* p) { f32x4 v; __builtin_memcpy(&v, p, 16); return v; }
__device__ __forceinline__ void stf4(void* p, f32x4 v) { __builtin_memcpy(p, &v, 16); }
__device__ __forceinline__ s16x8 frag16(const void* p) { s16x8 v; __builtin_memcpy(&v, p, 16); return v; }
__device__ __forceinline__ s16x8 pack8(f32x4 lo, f32x4 hi) {
  union { unsigned u[4]; s16x8 s; } c;
  c.u[0] = cvt2(lo.x, lo.y); c.u[1] = cvt2(lo.z, lo.w);
  c.u[2] = cvt2(hi.x, hi.y); c.u[3] = cvt2(hi.z, hi.w);
  return c.s;
}

// ---------------------------------------------------------------------------
// K1: QKV projection via MFMA (r22 verbatim). Grid (16 nt, 4 hp, 8 b).
// ---------------------------------------------------------------------------
__global__ __launch_bounds__(256) void r33_qkv(
    const float* __restrict__ x,
    const float* __restrict__ Wq, const float* __restrict__ bq,
    const float* __restrict__ Wk, const float* __restrict__ bk,
    const float* __restrict__ Wv, const float* __restrict__ bv,
    u16* __restrict__ qo, u16* __restrict__ ko, u16* __restrict__ vo)
{
  __shared__ u16 xt[64][264];    // [n][c^msk(n)], row stride 528B
  __shared__ u16 wlds[192][40];

  const int t = threadIdx.x;
  const int ntile = blockIdx.x, hp = blockIdx.y, b = blockIdx.z;
  const int n0 = ntile * 64, h0 = hp * 2;
  const int w = t >> 6, lane = t & 63, l15 = lane & 15, quad = lane >> 4;
  const int oct = t & 7;

  {  // stage x^T, coalesced: pass p covers channels p*16..p*16+15.
    const int i = t & 15, co = t >> 4;           // i: n-quad, co: c within pass
    const float* xb = x + ((size_t)b * 256 + co) * 1024 + n0 + i * 4;
    const int msk = (i & 7) << 3;                // n>>2 == i
#pragma unroll
    for (int p = 0; p < 16; ++p) {
      const f32x4 a = ldf4(xb + (size_t)p * 16 * 1024);
      const int c = p * 16 + co;
#pragma unroll
      for (int j = 0; j < 4; ++j)
        xt[i * 4 + j][(c ^ msk)] = f2bf(a[j]);
    }
  }

  f32x4 acc[12];
#pragma unroll
  for (int i = 0; i < 12; ++i) acc[i] = (f32x4){0.f, 0.f, 0.f, 0.f};

  for (int ks = 0; ks < 8; ++ks) {
    __syncthreads();   // protect wlds reuse (and xt staging on ks=0)
    {  // stage W chunk, coalesced: 8 lanes x 16B = 128B row segment.
#pragma unroll
      for (int u = 0; u < 6; ++u) {
        const int row = (u * 256 + t) >> 3;      // 0..191
        const int m = row >> 6, hh = (row >> 5) & 1, rr = row & 31;
        const float* M = (m == 0) ? Wq : (m == 1) ? Wk : Wv;
        const f32x4 a = ldf4(M + (size_t)((h0 + hh) * 32 + rr) * 256
                             + ks * 32 + oct * 4);
        st8(&wlds[row][oct * 4], cvt2(a.x, a.y), cvt2(a.z, a.w));
      }
    }
    __syncthreads();

    const int nrow = w * 16 + l15;
    const s16x8 bfrag = frag16(
        &xt[nrow][(ks * 32 + quad * 8) ^ (((nrow >> 2) & 7) << 3)]);
#pragma unroll
    for (int mt = 0; mt < 12; ++mt) {
      const s16x8 af = frag16(&wlds[mt * 16 + l15][quad * 8]);
      acc[mt] = __builtin_amdgcn_mfma_f32_16x16x32_bf16(af, bfrag, acc[mt], 0, 0, 0);
    }
  }

  // epilogue: C/D row = quad*4+rr (d within 16), col = l15 (n within 16)
  const int n = n0 + w * 16 + l15;
  const int sig = n & 127;
  const int ntn = sig >> 4, q4 = (sig >> 2) & 3, rn = sig & 3;
  const int nperm = (n & ~127) | ((ntn >> 1) << 5) | (q4 << 3) | ((ntn & 1) << 2) | rn;
#pragma unroll
  for (int hh = 0; hh < 2; ++hh) {
    const int h = h0 + hh;
    const size_t bh = (size_t)(b * 8 + h);
    u16* qrow = qo + (bh * 1024 + n) * 32;
    u16* krow = ko + (bh * 1024 + n) * 32;
#pragma unroll
    for (int half = 0; half < 2; ++half) {
      const int d0 = half * 16 + quad * 4;
      const f32x4 aq = acc[0 + hh * 2 + half];
      const f32x4 ak = acc[4 + hh * 2 + half];
      const f32x4 av = acc[8 + hh * 2 + half];
      st4(qrow + d0,     cvt2((aq.x + bq[h * 32 + d0 + 0]) * QK_SCALE,
                              (aq.y + bq[h * 32 + d0 + 1]) * QK_SCALE));
      st4(qrow + d0 + 2, cvt2((aq.z + bq[h * 32 + d0 + 2]) * QK_SCALE,
                              (aq.w + bq[h * 32 + d0 + 3]) * QK_SCALE));
      st4(krow + d0,     cvt2(ak.x + bk[h * 32 + d0 + 0],
                              ak.y + bk[h * 32 + d0 + 1]));
      st4(krow + d0 + 2, cvt2(ak.z + bk[h * 32 + d0 + 2],
                              ak.w + bk[h * 32 + d0 + 3]));
#pragma unroll
      for (int rr = 0; rr < 4; ++rr) {
        const int d = d0 + rr;
        vo[(bh * 32 + d) * 1024 + nperm] = f2bf(av[rr] + bv[h * 32 + d]);
      }
    }
  }
}

// ---------------------------------------------------------------------------
// K2a: split-K flash attention. Grid 2048 1-D, swizzled:
// id = (bh&7) + 8*qtile + 128*half + 256*(bh>>3). Block (qtile,bh,half)
// processes keys [half*512, half*512+512) = 4 chunks of 128. Single-buffer
// LDS (18.9KB), 2 barriers/chunk, prefetch issued AFTER barrier-2 (r32).
// Writes UNNORMALIZED fp32 partials: pf[half][b][n][c] + ml[half][bh][n][2].
// ---------------------------------------------------------------------------
__global__ __launch_bounds__(256) void r33_attn_split(
    const u16* __restrict__ qw, const u16* __restrict__ kw,
    const u16* __restrict__ vw, float* __restrict__ pf,
    float* __restrict__ ml)
{
  __shared__ u16 klds[128][40];   // [key][d]   10240B
  __shared__ u16 vlds[32][136];   // [d][kperm]  8704B

  const int t = threadIdx.x;
  const int id = blockIdx.x;
  const int qtile = (id >> 3) & 15;
  const int half = (id >> 7) & 1;
  const int bh = (id & 7) + ((id >> 8) << 3);
  const int w = t >> 6, lane = t & 63, l15 = lane & 15, quad = lane >> 4;

  // B-frag: B[k=quad*8+j][n=l15] = Q[query w*16+l15][d=quad*8+j]
  const s16x8 qfrag = frag16(
      qw + ((size_t)bh * 1024 + qtile * 64 + w * 16 + l15) * 32 + quad * 8);

  // staging addresses (offset by this block's 512-key half)
  const u16* kbase = kw + ((size_t)bh * 1024 + half * 512 + (t >> 1)) * 32 + (t & 1) * 16;
  const u16* vbase = vw + ((size_t)bh * 32 + (t >> 3)) * 1024 + half * 512 + (t & 7) * 16;

  u16x8 gk0 = ld16(kbase), gk1 = ld16(kbase + 8);
  u16x8 gv0 = ld16(vbase), gv1 = ld16(vbase + 8);

  f32x4 o0 = {0.f, 0.f, 0.f, 0.f}, o1 = {0.f, 0.f, 0.f, 0.f};
  float mrun = -1e30f, lrun = 0.f;

  for (int kb = 0; kb < 4; ++kb) {
    if (kb) __syncthreads();       // readers of previous chunk done
    st16(&klds[t >> 1][(t & 1) * 16], gk0);
    st16(&klds[t >> 1][(t & 1) * 16 + 8], gk1);
    st16(&vlds[t >> 3][(t & 7) * 16], gv0);
    st16(&vlds[t >> 3][(t & 7) * 16 + 8], gv1);
    __syncthreads();               // staging visible

    if (kb < 3) {                  // prefetch AFTER barrier (r32 lesson)
      const u16* kn = kbase + (size_t)(kb + 1) * (128 * 32);
      const u16* vn = vbase + (size_t)(kb + 1) * 128;
      gk0 = ld16(kn); gk1 = ld16(kn + 8);
      gv0 = ld16(vn); gv1 = ld16(vn + 8);
    }

    // QK^T swapped: s[nt2][r] = S[key nt2*16+quad*4+r][query w*16+l15]
    f32x4 s[8];
    const f32x4 zz = {0.f, 0.f, 0.f, 0.f};
    __builtin_amdgcn_s_setprio(1);
#pragma unroll
    for (int nt2 = 0; nt2 < 8; ++nt2) {
      const s16x8 kf = frag16(&klds[nt2 * 16 + l15][quad * 8]);
      s[nt2] = __builtin_amdgcn_mfma_f32_16x16x32_bf16(kf, qfrag, zz, 0, 0, 0);
    }
    __builtin_amdgcn_s_setprio(0);

    // online softmax: in-lane over 32 keys + cross-quad reduce (xor 16,32)
    float mx = fmaxf(fmaxf(s[0][0], s[0][1]), fmaxf(s[0][2], s[0][3]));
#pragma unroll
    for (int nt2 = 1; nt2 < 8; ++nt2)
      mx = fmaxf(mx, fmaxf(fmaxf(s[nt2][0], s[nt2][1]),
                           fmaxf(s[nt2][2], s[nt2][3])));
    mx = fmaxf(mx, __shfl_xor(mx, 16));
    mx = fmaxf(mx, __shfl_xor(mx, 32));
    const float mnew = fmaxf(mrun, mx);
    const float alpha = exp2f(mrun - mnew);
    float rs = 0.f;
#pragma unroll
    for (int nt2 = 0; nt2 < 8; ++nt2) {
#pragma unroll
      for (int r = 0; r < 4; ++r) {
        s[nt2][r] = exp2f(s[nt2][r] - mnew);
        rs += s[nt2][r];
      }
    }
    rs += __shfl_xor(rs, 16);
    rs += __shfl_xor(rs, 32);
    lrun = lrun * alpha + rs;
    mrun = mnew;
#pragma unroll
    for (int r = 0; r < 4; ++r) { o0[r] *= alpha; o1[r] *= alpha; }

    // PV: O^T = V^T * P^T; B-frag slot (quad, j=hi*4+r) = p[2ks+hi][r]
    __builtin_amdgcn_s_setprio(1);
#pragma unroll
    for (int ks = 0; ks < 4; ++ks) {
      const s16x8 pfr = pack8(s[2 * ks], s[2 * ks + 1]);
      const s16x8 vf0 = frag16(&vlds[l15][ks * 32 + quad * 8]);
      const s16x8 vf1 = frag16(&vlds[16 + l15][ks * 32 + quad * 8]);
      o0 = __builtin_amdgcn_mfma_f32_16x16x32_bf16(vf0, pfr, o0, 0, 0, 0);
      o1 = __builtin_amdgcn_mfma_f32_16x16x32_bf16(vf1, pfr, o1, 0, 0, 0);
    }
    __builtin_amdgcn_s_setprio(0);
  }

  // epilogue: UNNORMALIZED partials. pf[half][b][n][c], c = hh*32 + d.
  // Lane writes d=quad*4..+3 (stf4) and d+16 (stf4). ml by quad==0 lanes.
  const int b = bh >> 3, hh = bh & 7;
  const int n = qtile * 64 + w * 16 + l15;
  float* pbase = pf + (((size_t)half * 8 + b) * 1024 + n) * 256 + hh * 32 + quad * 4;
  stf4(pbase, o0);
  stf4(pbase + 16, o1);
  if (quad == 0) {
    float* mlp = ml + ((size_t)half * 65536 + (size_t)bh * 1024 + n) * 2;
    mlp[0] = mrun;
    mlp[1] = lrun;
  }
}

// ---------------------------------------------------------------------------
// K2b: merge the 2 half partials (flash combine) -> bf16 ows[b][n][c].
// Grid 1024 x 256 thr; thread handles 2 f32x4 groups (coalesced 16B).
// ---------------------------------------------------------------------------
__global__ __launch_bounds__(256) void r33_merge(
    const float* __restrict__ pf, const float* __restrict__ ml,
    u16* __restrict__ ows)
{
  const int t = threadIdx.x, g = blockIdx.x;
#pragma unroll
  for (int u = 0; u < 2; ++u) {
    const int idx = g * 512 + u * 256 + t;       // 0..524287
    const int c4 = idx & 63;                     // c = c4*4
    const int bn = idx >> 6;                     // b*1024 + n
    const int b = bn >> 10, n = bn & 1023;
    const int hh = c4 >> 3;                      // c>>5
    const size_t mlo = ((size_t)b * 8 + hh) * 1024 + n;
    const float m1 = ml[mlo * 2], l1 = ml[mlo * 2 + 1];
    const float m2 = ml[(65536 + mlo) * 2], l2 = ml[(65536 + mlo) * 2 + 1];
    const float M = fmaxf(m1, m2);
    const float s1 = exp2f(m1 - M), s2 = exp2f(m2 - M);
    const float inv = 1.0f / (s1 * l1 + s2 * l2);
    const size_t po = (size_t)bn * 256 + c4 * 4;
    const f32x4 p1 = ldf4(pf + po);
    const f32x4 p2 = ldf4(pf + 2097152 + po);
    f32x4 o;
#pragma unroll
    for (int r = 0; r < 4; ++r) o[r] = (s1 * p1[r] + s2 * p2[r]) * inv;
    st8(ows + po, cvt2(o.x, o.y), cvt2(o.z, o.w));
  }
}

// ---------------------------------------------------------------------------
// K3: out-projection, K2-shaped (r29 verbatim). Grid (32 nt, 8 b, 4 ocq).
// ---------------------------------------------------------------------------
__global__ __launch_bounds__(256) void r33_oproj(
    const u16* __restrict__ ows,
    const float* __restrict__ Wo, const float* __restrict__ bo,
    float* __restrict__ out)
{
  __shared__ u16 o2t[32][256];   // 16384B
  __shared__ u16 wl[64][40];     //  5120B

  const int t = threadIdx.x;
  const int nt = blockIdx.x, b = blockIdx.y, q = blockIdx.z;
  const int w = t >> 6, lane = t & 63, l15 = lane & 15, quad = lane >> 4;

  {  // stage o-tile: pure copy, 4 passes x (8 rows x 32 groups of 16B).
    const int g = t & 31, nr = t >> 5;
#pragma unroll
    for (int p = 0; p < 4; ++p) {
      const int n = p * 8 + nr;
      const u16* src = ows + ((size_t)b * 1024 + nt * 32 + n) * 256 + g * 8;
      st16(&o2t[n][(g ^ (n & 7)) << 3], ld16(src));
    }
  }

  // Wo reg-prefetch: row rl = t>>2 (4 thr/row), cols cq*8..+7 of the chunk
  const int rl = t >> 2, cq = t & 3;
  const float* wsrc = Wo + (size_t)(q * 64 + rl) * 256 + cq * 8;
  unsigned wr0, wr1, wr2, wr3;
  {
    const f32x4 a = ldf4(wsrc), c = ldf4(wsrc + 4);   // ks = 0
    wr0 = cvt2(a.x, a.y); wr1 = cvt2(a.z, a.w);
    wr2 = cvt2(c.x, c.y); wr3 = cvt2(c.z, c.w);
  }

  f32x4 acc0 = {0.f, 0.f, 0.f, 0.f}, acc1 = {0.f, 0.f, 0.f, 0.f};
  const int m0 = l15 & 7;   // swizzle key (rows l15 / 16+l15 share it)

  for (int ks = 0; ks < 8; ++ks) {
    __syncthreads();   // wl readers done (and o2t staged, on ks=0)
    st8(&wl[rl][cq * 8], wr0, wr1);
    st8(&wl[rl][cq * 8 + 4], wr2, wr3);
    __syncthreads();

    f32x4 na, nc;
    if (ks < 7) { na = ldf4(wsrc + (ks + 1) * 32); nc = ldf4(wsrc + (ks + 1) * 32 + 4); }

    const s16x8 af = frag16(&wl[w * 16 + l15][quad * 8]);
    const s16x8 b0 = frag16(&o2t[l15][((ks * 4 + quad) ^ m0) << 3]);
    const s16x8 b1 = frag16(&o2t[16 + l15][((ks * 4 + quad) ^ m0) << 3]);
    acc0 = __builtin_amdgcn_mfma_f32_16x16x32_bf16(af, b0, acc0, 0, 0, 0);
    acc1 = __builtin_amdgcn_mfma_f32_16x16x32_bf16(af, b1, acc1, 0, 0, 0);

    if (ks < 7) {
      wr0 = cvt2(na.x, na.y); wr1 = cvt2(na.z, na.w);
      wr2 = cvt2(nc.x, nc.y); wr3 = cvt2(nc.z, nc.w);
    }
  }

  // epilogue: C/D row = quad*4+r -> oc = q*64 + w*16 + quad*4 + r; col = l15
#pragma unroll
  for (int r = 0; r < 4; ++r) {
    const int oc = q * 64 + w * 16 + quad * 4 + r;
    const float bov = bo[oc];
    out[((size_t)b * 256 + oc) * 1024 + nt * 32 + l15]      = acc0[r] + bov;
    out[((size_t)b * 256 + oc) * 1024 + nt * 32 + 16 + l15] = acc1[r] + bov;
  }
}

// ---------------------------------------------------------------------------
// Launch: qkv, attn_split (2048 blocks), merge, oproj.
// ---------------------------------------------------------------------------
extern "C" void kernel_launch(void* const* d_in, const int* in_sizes, int n_in,
                              void* d_out, int out_size, void* d_ws, size_t ws_size,
                              hipStream_t stream) {
  (void)in_sizes; (void)n_in; (void)out_size; (void)ws_size;
  const float* x  = (const float*)d_in[0];
  const float* Wq = (const float*)d_in[1];
  const float* bq = (const float*)d_in[2];
  const float* Wk = (const float*)d_in[3];
  const float* bk = (const float*)d_in[4];
  const float* Wv = (const float*)d_in[5];
  const float* bv = (const float*)d_in[6];
  const float* Wo = (const float*)d_in[7];
  const float* bo = (const float*)d_in[8];
  float* out = (float*)d_out;

  char* ws = (char*)d_ws;
  u16*   qw  = (u16*)(ws);                    // [bh][n][d] bf16, 4MB
  u16*   kw  = (u16*)(ws + (4u << 20));       // [bh][n][d] bf16, 4MB
  u16*   vw  = (u16*)(ws + (8u << 20));       // [bh][d][nperm] bf16, 4MB
  u16*   ows = (u16*)(ws + (12u << 20));      // [b][n][c] bf16, 4MB
  float* pf  = (float*)(ws + (16u << 20));    // [2][b][n][c] fp32, 16MB
  float* ml  = (float*)(ws + (32u << 20));    // [2][bh][n][2] fp32, 1MB

  r33_qkv<<<dim3(16, 4, 8), 256, 0, stream>>>(
      x, Wq, bq, Wk, bk, Wv, bv, qw, kw, vw);
  r33_attn_split<<<dim3(2048), 256, 0, stream>>>(qw, kw, vw, pf, ml);
  r33_merge<<<dim3(1024), 256, 0, stream>>>(pf, ml, ows);
  r33_oproj<<<dim3(32, 8, 4), 256, 0, stream>>>(ows, Wo, bo, out);
}

// Round 17
// 124.942 us; speedup vs baseline: 1.0695x; 1.0695x over previous
//
#include <hip/hip_runtime.h>
#include <math.h>

// Problem: B=8, C=256, N=H*W=1024, nh=8, dk=dv=32. fp32 in/out, bf16 ws.
// Round 34 = FINAL REVERT to r32 (best measured: 124.99us).
// Ledger (measured across r24/r27/r28 probes): ~83us fixed harness cost
// (ws re-poison fill ~44 + launch/sync framing ~39) + K1 ~6 + K2 ~31 +
// K3 ~5. K2 is invariant ~31us across nine structural variants (barrier
// count, dbuf, XCD swizzle, setprio, prefetch placement, occupancy,
// zero-LDS free-run, split-K) -- r33's split-K (133.6) and r31's zero-LDS
// (143) both regressed. This structure is the measured optimum.
typedef unsigned short u16;
typedef __attribute__((ext_vector_type(8))) unsigned short u16x8;
typedef __attribute__((ext_vector_type(8))) short s16x8;   // MFMA A/B frag
typedef __attribute__((ext_vector_type(4))) float f32x4;   // MFMA C/D

// logits scale 1/sqrt(32) folded with log2(e) so softmax uses exp2 directly
#define QK_SCALE (0.17677669529663687f * 1.4426950408889634f)

__device__ __forceinline__ unsigned cvt2(float lo, float hi) {
  unsigned r;  // D[15:0]=bf16_rne(lo), D[31:16]=bf16_rne(hi)
  asm("v_cvt_pk_bf16_f32 %0, %1, %2" : "=v"(r) : "v"(lo), "v"(hi));
  return r;
}
__device__ __forceinline__ u16 f2bf(float f) { return (u16)cvt2(f, f); }
__device__ __forceinline__ u16x8 ld16(const void* p) { u16x8 v; __builtin_memcpy(&v, p, 16); return v; }
__device__ __forceinline__ void st16(void* p, u16x8 v) { __builtin_memcpy(p, &v, 16); }
__device__ __forceinline__ void st4(void* p, unsigned v) { __builtin_memcpy(p, &v, 4); }
__device__ __forceinline__ void st8(void* p, unsigned lo, unsigned hi) {
  unsigned long long v = ((unsigned long long)hi << 32) | (unsigned long long)lo;
  __builtin_memcpy(p, &v, 8);
}
__device__ __forceinline__ f32x4 ldf4(const void* p) { f32x4 v; __builtin_memcpy(&v, p, 16); return v; }
__device__ __forceinline__ s16x8 frag16(const void* p) { s16x8 v; __builtin_memcpy(&v, p, 16); return v; }
__device__ __forceinline__ s16x8 pack8(f32x4 lo, f32x4 hi) {
  union { unsigned u[4]; s16x8 s; } c;
  c.u[0] = cvt2(lo.x, lo.y); c.u[1] = cvt2(lo.z, lo.w);
  c.u[2] = cvt2(hi.x, hi.y); c.u[3] = cvt2(hi.z, hi.w);
  return c.s;
}

// ---------------------------------------------------------------------------
// K1: QKV projection via MFMA (r22 verbatim). Grid (16 nt, 4 hp, 8 b).
// ---------------------------------------------------------------------------
__global__ __launch_bounds__(256) void r34_qkv(
    const float* __restrict__ x,
    const float* __restrict__ Wq, const float* __restrict__ bq,
    const float* __restrict__ Wk, const float* __restrict__ bk,
    const float* __restrict__ Wv, const float* __restrict__ bv,
    u16* __restrict__ qo, u16* __restrict__ ko, u16* __restrict__ vo)
{
  __shared__ u16 xt[64][264];    // [n][c^msk(n)], row stride 528B
  __shared__ u16 wlds[192][40];

  const int t = threadIdx.x;
  const int ntile = blockIdx.x, hp = blockIdx.y, b = blockIdx.z;
  const int n0 = ntile * 64, h0 = hp * 2;
  const int w = t >> 6, lane = t & 63, l15 = lane & 15, quad = lane >> 4;
  const int oct = t & 7;

  {  // stage x^T, coalesced: pass p covers channels p*16..p*16+15.
    const int i = t & 15, co = t >> 4;           // i: n-quad, co: c within pass
    const float* xb = x + ((size_t)b * 256 + co) * 1024 + n0 + i * 4;
    const int msk = (i & 7) << 3;                // n>>2 == i
#pragma unroll
    for (int p = 0; p < 16; ++p) {
      const f32x4 a = ldf4(xb + (size_t)p * 16 * 1024);
      const int c = p * 16 + co;
#pragma unroll
      for (int j = 0; j < 4; ++j)
        xt[i * 4 + j][(c ^ msk)] = f2bf(a[j]);
    }
  }

  f32x4 acc[12];
#pragma unroll
  for (int i = 0; i < 12; ++i) acc[i] = (f32x4){0.f, 0.f, 0.f, 0.f};

  for (int ks = 0; ks < 8; ++ks) {
    __syncthreads();   // protect wlds reuse (and xt staging on ks=0)
    {  // stage W chunk, coalesced: 8 lanes x 16B = 128B row segment.
#pragma unroll
      for (int u = 0; u < 6; ++u) {
        const int row = (u * 256 + t) >> 3;      // 0..191
        const int m = row >> 6, hh = (row >> 5) & 1, rr = row & 31;
        const float* M = (m == 0) ? Wq : (m == 1) ? Wk : Wv;
        const f32x4 a = ldf4(M + (size_t)((h0 + hh) * 32 + rr) * 256
                             + ks * 32 + oct * 4);
        st8(&wlds[row][oct * 4], cvt2(a.x, a.y), cvt2(a.z, a.w));
      }
    }
    __syncthreads();

    const int nrow = w * 16 + l15;
    const s16x8 bfrag = frag16(
        &xt[nrow][(ks * 32 + quad * 8) ^ (((nrow >> 2) & 7) << 3)]);
#pragma unroll
    for (int mt = 0; mt < 12; ++mt) {
      const s16x8 af = frag16(&wlds[mt * 16 + l15][quad * 8]);
      acc[mt] = __builtin_amdgcn_mfma_f32_16x16x32_bf16(af, bfrag, acc[mt], 0, 0, 0);
    }
  }

  // epilogue: C/D row = quad*4+rr (d within 16), col = l15 (n within 16)
  const int n = n0 + w * 16 + l15;
  const int sig = n & 127;
  const int ntn = sig >> 4, q4 = (sig >> 2) & 3, rn = sig & 3;
  const int nperm = (n & ~127) | ((ntn >> 1) << 5) | (q4 << 3) | ((ntn & 1) << 2) | rn;
#pragma unroll
  for (int hh = 0; hh < 2; ++hh) {
    const int h = h0 + hh;
    const size_t bh = (size_t)(b * 8 + h);
    u16* qrow = qo + (bh * 1024 + n) * 32;
    u16* krow = ko + (bh * 1024 + n) * 32;
#pragma unroll
    for (int half = 0; half < 2; ++half) {
      const int d0 = half * 16 + quad * 4;
      const f32x4 aq = acc[0 + hh * 2 + half];
      const f32x4 ak = acc[4 + hh * 2 + half];
      const f32x4 av = acc[8 + hh * 2 + half];
      st4(qrow + d0,     cvt2((aq.x + bq[h * 32 + d0 + 0]) * QK_SCALE,
                              (aq.y + bq[h * 32 + d0 + 1]) * QK_SCALE));
      st4(qrow + d0 + 2, cvt2((aq.z + bq[h * 32 + d0 + 2]) * QK_SCALE,
                              (aq.w + bq[h * 32 + d0 + 3]) * QK_SCALE));
      st4(krow + d0,     cvt2(ak.x + bk[h * 32 + d0 + 0],
                              ak.y + bk[h * 32 + d0 + 1]));
      st4(krow + d0 + 2, cvt2(ak.z + bk[h * 32 + d0 + 2],
                              ak.w + bk[h * 32 + d0 + 3]));
#pragma unroll
      for (int rr = 0; rr < 4; ++rr) {
        const int d = d0 + rr;
        vo[(bh * 32 + d) * 1024 + nperm] = f2bf(av[rr] + bv[h * 32 + d]);
      }
    }
  }
}

// ---------------------------------------------------------------------------
// K2: flash attention, swapped QK^T, zero-LDS P. 1-D grid 1024, bh-per-XCD
// swizzle. Double-buffered K/V LDS, ONE barrier per 128-key chunk; prefetch
// issues AFTER the barrier (lands during compute, consumed at next chunk's
// stores). setprio(1) around MFMA clusters. Epilogue: bf16 ows[b][n][c].
// ---------------------------------------------------------------------------
__global__ __launch_bounds__(256) void r34_attn(
    const u16* __restrict__ qw, const u16* __restrict__ kw,
    const u16* __restrict__ vw, u16* __restrict__ ows)
{
  __shared__ u16 klds[2][128][40];   // 20480B
  __shared__ u16 vlds[2][32][136];   // 17408B

  const int t = threadIdx.x;
  const int id = blockIdx.x;
  const int qtile = (id >> 3) & 15;
  const int bh = (id & 7) + ((id >> 7) << 3);
  const int w = t >> 6, lane = t & 63, l15 = lane & 15, quad = lane >> 4;

  // B-frag: B[k=quad*8+j][n=l15] = Q[query w*16+l15][d=quad*8+j]
  const s16x8 qfrag = frag16(
      qw + ((size_t)bh * 1024 + qtile * 64 + w * 16 + l15) * 32 + quad * 8);

  // staging addresses: K row t>>1 (2 thr/row), V row t>>3 (8 thr/row)
  const u16* kbase = kw + ((size_t)bh * 1024 + (t >> 1)) * 32 + (t & 1) * 16;
  const u16* vbase = vw + ((size_t)bh * 32 + (t >> 3)) * 1024 + (t & 7) * 16;

  u16x8 gk0 = ld16(kbase), gk1 = ld16(kbase + 8);
  u16x8 gv0 = ld16(vbase), gv1 = ld16(vbase + 8);

  f32x4 o0 = {0.f, 0.f, 0.f, 0.f}, o1 = {0.f, 0.f, 0.f, 0.f};
  float mrun = -1e30f, lrun = 0.f;

  for (int kb = 0; kb < 8; ++kb) {
    const int cur = kb & 1;
    // store prefetched chunk into the idle buffer (consumes gk/gv: the
    // compiler's vmcnt wait lands here, a full compute phase after issue).
    st16(&klds[cur][t >> 1][(t & 1) * 16], gk0);
    st16(&klds[cur][t >> 1][(t & 1) * 16 + 8], gk1);
    st16(&vlds[cur][t >> 3][(t & 7) * 16], gv0);
    st16(&vlds[cur][t >> 3][(t & 7) * 16 + 8], gv1);
    __syncthreads();               // drains LDS stores only; loads already consumed

    if (kb < 7) {                  // prefetch AFTER barrier: overlaps compute
      const u16* kn = kbase + (size_t)(kb + 1) * (128 * 32);
      const u16* vn = vbase + (size_t)(kb + 1) * 128;
      gk0 = ld16(kn); gk1 = ld16(kn + 8);
      gv0 = ld16(vn); gv1 = ld16(vn + 8);
    }

    // QK^T swapped: s[nt2][r] = S[key nt2*16+quad*4+r][query w*16+l15]
    f32x4 s[8];
    const f32x4 zz = {0.f, 0.f, 0.f, 0.f};
    __builtin_amdgcn_s_setprio(1);
#pragma unroll
    for (int nt2 = 0; nt2 < 8; ++nt2) {
      const s16x8 kf = frag16(&klds[cur][nt2 * 16 + l15][quad * 8]);
      s[nt2] = __builtin_amdgcn_mfma_f32_16x16x32_bf16(kf, qfrag, zz, 0, 0, 0);
    }
    __builtin_amdgcn_s_setprio(0);

    // online softmax: in-lane over 32 keys + cross-quad reduce (xor 16,32)
    float mx = fmaxf(fmaxf(s[0][0], s[0][1]), fmaxf(s[0][2], s[0][3]));
#pragma unroll
    for (int nt2 = 1; nt2 < 8; ++nt2)
      mx = fmaxf(mx, fmaxf(fmaxf(s[nt2][0], s[nt2][1]),
                           fmaxf(s[nt2][2], s[nt2][3])));
    mx = fmaxf(mx, __shfl_xor(mx, 16));
    mx = fmaxf(mx, __shfl_xor(mx, 32));
    const float mnew = fmaxf(mrun, mx);
    const float alpha = exp2f(mrun - mnew);
    float rs = 0.f;
#pragma unroll
    for (int nt2 = 0; nt2 < 8; ++nt2) {
#pragma unroll
      for (int r = 0; r < 4; ++r) {
        s[nt2][r] = exp2f(s[nt2][r] - mnew);
        rs += s[nt2][r];
      }
    }
    rs += __shfl_xor(rs, 16);
    rs += __shfl_xor(rs, 32);
    lrun = lrun * alpha + rs;
    mrun = mnew;
#pragma unroll
    for (int r = 0; r < 4; ++r) { o0[r] *= alpha; o1[r] *= alpha; }

    // PV: O^T = V^T * P^T; B-frag slot (quad, j=hi*4+r) = p[2ks+hi][r]
    __builtin_amdgcn_s_setprio(1);
#pragma unroll
    for (int ks = 0; ks < 4; ++ks) {
      const s16x8 pf  = pack8(s[2 * ks], s[2 * ks + 1]);
      const s16x8 vf0 = frag16(&vlds[cur][l15][ks * 32 + quad * 8]);
      const s16x8 vf1 = frag16(&vlds[cur][16 + l15][ks * 32 + quad * 8]);
      o0 = __builtin_amdgcn_mfma_f32_16x16x32_bf16(vf0, pf, o0, 0, 0, 0);
      o1 = __builtin_amdgcn_mfma_f32_16x16x32_bf16(vf1, pf, o1, 0, 0, 0);
    }
    __builtin_amdgcn_s_setprio(0);
  }

  // epilogue: lane holds O^T[d][query l15]; write bf16 to ows[b][n][c],
  // c = hh*32 + d. Two 8B stores (d = quad*4..+3 and +16..+19).
  const float inv = 1.0f / lrun;
  const int b = bh >> 3, hh = bh & 7;
  u16* obase = ows + ((size_t)b * 1024 + qtile * 64 + w * 16 + l15) * 256
             + hh * 32 + quad * 4;
  st8(obase,      cvt2(o0[0] * inv, o0[1] * inv), cvt2(o0[2] * inv, o0[3] * inv));
  st8(obase + 16, cvt2(o1[0] * inv, o1[1] * inv), cvt2(o1[2] * inv, o1[3] * inv));
}

// ---------------------------------------------------------------------------
// K3: out-projection, K2-shaped (r29 verbatim). Grid (32 nt, 8 b, 4 ocq).
// ---------------------------------------------------------------------------
__global__ __launch_bounds__(256) void r34_oproj(
    const u16* __restrict__ ows,
    const float* __restrict__ Wo, const float* __restrict__ bo,
    float* __restrict__ out)
{
  __shared__ u16 o2t[32][256];   // 16384B
  __shared__ u16 wl[64][40];     //  5120B

  const int t = threadIdx.x;
  const int nt = blockIdx.x, b = blockIdx.y, q = blockIdx.z;
  const int w = t >> 6, lane = t & 63, l15 = lane & 15, quad = lane >> 4;

  {  // stage o-tile: pure copy, 4 passes x (8 rows x 32 groups of 16B).
    const int g = t & 31, nr = t >> 5;
#pragma unroll
    for (int p = 0; p < 4; ++p) {
      const int n = p * 8 + nr;
      const u16* src = ows + ((size_t)b * 1024 + nt * 32 + n) * 256 + g * 8;
      st16(&o2t[n][(g ^ (n & 7)) << 3], ld16(src));
    }
  }

  // Wo reg-prefetch: row rl = t>>2 (4 thr/row), cols cq*8..+7 of the chunk
  const int rl = t >> 2, cq = t & 3;
  const float* wsrc = Wo + (size_t)(q * 64 + rl) * 256 + cq * 8;
  unsigned wr0, wr1, wr2, wr3;
  {
    const f32x4 a = ldf4(wsrc), c = ldf4(wsrc + 4);   // ks = 0
    wr0 = cvt2(a.x, a.y); wr1 = cvt2(a.z, a.w);
    wr2 = cvt2(c.x, c.y); wr3 = cvt2(c.z, c.w);
  }

  f32x4 acc0 = {0.f, 0.f, 0.f, 0.f}, acc1 = {0.f, 0.f, 0.f, 0.f};
  const int m0 = l15 & 7;   // swizzle key (rows l15 / 16+l15 share it)

  for (int ks = 0; ks < 8; ++ks) {
    __syncthreads();   // wl readers done (and o2t staged, on ks=0)
    st8(&wl[rl][cq * 8], wr0, wr1);
    st8(&wl[rl][cq * 8 + 4], wr2, wr3);
    __syncthreads();

    f32x4 na, nc;
    if (ks < 7) { na = ldf4(wsrc + (ks + 1) * 32); nc = ldf4(wsrc + (ks + 1) * 32 + 4); }

    const s16x8 af = frag16(&wl[w * 16 + l15][quad * 8]);
    const s16x8 b0 = frag16(&o2t[l15][((ks * 4 + quad) ^ m0) << 3]);
    const s16x8 b1 = frag16(&o2t[16 + l15][((ks * 4 + quad) ^ m0) << 3]);
    acc0 = __builtin_amdgcn_mfma_f32_16x16x32_bf16(af, b0, acc0, 0, 0, 0);
    acc1 = __builtin_amdgcn_mfma_f32_16x16x32_bf16(af, b1, acc1, 0, 0, 0);

    if (ks < 7) {
      wr0 = cvt2(na.x, na.y); wr1 = cvt2(na.z, na.w);
      wr2 = cvt2(nc.x, nc.y); wr3 = cvt2(nc.z, nc.w);
    }
  }

  // epilogue: C/D row = quad*4+r -> oc = q*64 + w*16 + quad*4 + r; col = l15
#pragma unroll
  for (int r = 0; r < 4; ++r) {
    const int oc = q * 64 + w * 16 + quad * 4 + r;
    const float bov = bo[oc];
    out[((size_t)b * 256 + oc) * 1024 + nt * 32 + l15]      = acc0[r] + bov;
    out[((size_t)b * 256 + oc) * 1024 + nt * 32 + 16 + l15] = acc1[r] + bov;
  }
}

// ---------------------------------------------------------------------------
// Launch: qkv, attn (1-D swizzled grid), oproj.
// ---------------------------------------------------------------------------
extern "C" void kernel_launch(void* const* d_in, const int* in_sizes, int n_in,
                              void* d_out, int out_size, void* d_ws, size_t ws_size,
                              hipStream_t stream) {
  (void)in_sizes; (void)n_in; (void)out_size; (void)ws_size;
  const float* x  = (const float*)d_in[0];
  const float* Wq = (const float*)d_in[1];
  const float* bq = (const float*)d_in[2];
  const float* Wk = (const float*)d_in[3];
  const float* bk = (const float*)d_in[4];
  const float* Wv = (const float*)d_in[5];
  const float* bv = (const float*)d_in[6];
  const float* Wo = (const float*)d_in[7];
  const float* bo = (const float*)d_in[8];
  float* out = (float*)d_out;

  char* ws = (char*)d_ws;
  u16* qw  = (u16*)(ws);                     // [bh][n][d] bf16, 4MB
  u16* kw  = (u16*)(ws + (4u << 20));        // [bh][n][d] bf16, 4MB
  u16* vw  = (u16*)(ws + (8u << 20));        // [bh][d][nperm] bf16, 4MB
  u16* ows = (u16*)(ws + (12u << 20));       // [b][n][c] bf16, 4MB

  r34_qkv<<<dim3(16, 4, 8), 256, 0, stream>>>(
      x, Wq, bq, Wk, bk, Wv, bv, qw, kw, vw);
  r34_attn<<<dim3(1024), 256, 0, stream>>>(qw, kw, vw, ows);
  r34_oproj<<<dim3(32, 8, 4), 256, 0, stream>>>(ows, Wo, bo, out);
}